// Round 6
// baseline (348.675 us; speedup 1.0000x reference)
//
#include <hip/hip_runtime.h>

// GAT encoder, 3 layers. N=50000, E=800000, Fin=128.
// R5 -> R6:
//  * ssrc now packs src|dst<<16 (N<65536); bucket_sort slimmed (no 64KB LDS).
//  * new edgew_kernel: per-edge softmax weights w[h][k]=exp(e_k - e_self(dst))
//    computed once per edge (was recomputed by 16 lanes/head in aggr).
//  * aggr_kernel inner loop reduced to w-load + h-gather + FMA, 32-bit addrs.

#define NEG_SLOPE 0.2f

typedef _Float16 f16;
typedef f16 f16x8 __attribute__((ext_vector_type(8)));
typedef f16 f16x4 __attribute__((ext_vector_type(4)));
typedef f16 f16x2 __attribute__((ext_vector_type(2)));
typedef float f32x4 __attribute__((ext_vector_type(4)));

__device__ __forceinline__ float lrelu(float v) { return v > 0.f ? v : NEG_SLOPE * v; }

// ---------------- CSR build: two-level counting sort ----------------

__global__ void fill_zero_kernel(int* __restrict__ p, int n) {
    int i = blockIdx.x * blockDim.x + threadIdx.x;
    if (i < n) p[i] = 0;
}

__global__ __launch_bounds__(256) void bucket_count_kernel(const int* __restrict__ dst, int E,
                                                           int* __restrict__ bcount) {
    __shared__ int lh[256];
    lh[threadIdx.x] = 0;
    __syncthreads();
    int stride = gridDim.x * 256 * 4;
    for (int i = (blockIdx.x * 256 + threadIdx.x) * 4; i < E; i += stride) {
        int4 d = *(const int4*)&dst[i];
        atomicAdd(&lh[d.x >> 8], 1);
        atomicAdd(&lh[d.y >> 8], 1);
        atomicAdd(&lh[d.z >> 8], 1);
        atomicAdd(&lh[d.w >> 8], 1);
    }
    __syncthreads();
    int v = lh[threadIdx.x];
    if (v > 0) atomicAdd(&bcount[threadIdx.x], v);
}

__global__ __launch_bounds__(256) void bucket_scan_kernel(const int* __restrict__ bcount, int NBK,
                                                          int* __restrict__ bbase,
                                                          int* __restrict__ bcursor,
                                                          int* __restrict__ offsets, int N) {
    int t = threadIdx.x;
    int own = (t < NBK) ? bcount[t] : 0;
    int v = own;
    int lane = t & 63, wid = t >> 6;
#pragma unroll
    for (int off = 1; off < 64; off <<= 1) {
        int u = __shfl_up(v, off);
        if (lane >= off) v += u;
    }
    __shared__ int ws[4];
    if (lane == 63) ws[wid] = v;
    __syncthreads();
    int add = 0;
    for (int w = 0; w < wid; ++w) add += ws[w];
    v += add;
    int exc = v - own;
    if (t < NBK) {
        bbase[t] = exc;
        bcursor[t] = exc;
    }
    if (t == 255) {
        bbase[NBK] = v;
        offsets[N] = v;
    }
}

#define SC_TILE 4096
__global__ __launch_bounds__(256) void bucket_scatter_kernel(const int* __restrict__ src,
                                                             const int* __restrict__ dst, int E,
                                                             int* __restrict__ bcursor,
                                                             unsigned int* __restrict__ staging) {
    __shared__ int lh[256];
    __shared__ int lcur[256];
    int tid = threadIdx.x;
    lh[tid] = 0;
    __syncthreads();
    int base = blockIdx.x * SC_TILE + tid * 16;
    int sv[16], dv[16];
    bool act = base < E;
    if (act) {
#pragma unroll
        for (int q = 0; q < 4; ++q) {
            *(int4*)&sv[q * 4] = *(const int4*)&src[base + q * 4];
            *(int4*)&dv[q * 4] = *(const int4*)&dst[base + q * 4];
        }
#pragma unroll
        for (int j = 0; j < 16; ++j) atomicAdd(&lh[dv[j] >> 8], 1);
    }
    __syncthreads();
    int c = lh[tid];
    if (c > 0) lcur[tid] = atomicAdd(&bcursor[tid], c);
    __syncthreads();
    if (act) {
#pragma unroll
        for (int j = 0; j < 16; ++j) {
            int b = dv[j] >> 8;
            int pos = atomicAdd(&lcur[b], 1);
            staging[pos] = (unsigned int)sv[j] | ((unsigned int)(dv[j] & 255) << 16);
        }
    }
}

// One block per bucket: local 256-hist+scan -> offsets + in-bucket rank.
// Output ssrc[k] = src | full_dst<<16.
__global__ __launch_bounds__(256) void bucket_sort_kernel(const unsigned int* __restrict__ staging,
                                                          const int* __restrict__ bbase,
                                                          int* __restrict__ offsets,
                                                          int* __restrict__ ssrc, int N) {
    __shared__ int lh[256];
    __shared__ int ws[4];
    int b = blockIdx.x;
    int tid = threadIdx.x;
    int s = bbase[b], e = bbase[b + 1];
    int cnt = e - s;
    lh[tid] = 0;
    __syncthreads();
    for (int i = tid; i < cnt; i += 256) atomicAdd(&lh[staging[s + i] >> 16], 1);
    __syncthreads();
    int own = lh[tid];
    int v = own;
    int lane = tid & 63, wid = tid >> 6;
#pragma unroll
    for (int off = 1; off < 64; off <<= 1) {
        int u = __shfl_up(v, off);
        if (lane >= off) v += u;
    }
    if (lane == 63) ws[wid] = v;
    __syncthreads();
    int add = 0;
    for (int w = 0; w < wid; ++w) add += ws[w];
    int exc = v + add - own;
    int dstn = (b << 8) + tid;
    if (dstn < N) offsets[dstn] = s + exc;
    __syncthreads();
    lh[tid] = exc;
    __syncthreads();
    for (int i = tid; i < cnt; i += 256) {
        unsigned int rec = staging[s + i];
        int dlow = rec >> 16;
        int r = atomicAdd(&lh[dlow], 1);
        unsigned int full = (rec & 0xFFFFu) | ((unsigned int)((b << 8) | dlow) << 16);
        ssrc[s + r] = (int)full;
    }
}

// ---------------- fp16 splits ----------------

__global__ void split_x_kernel(const float* __restrict__ x, f16* __restrict__ xh,
                               f16* __restrict__ xl, int total4) {
    int i = blockIdx.x * blockDim.x + threadIdx.x;
    if (i >= total4) return;
    float4 v = *(const float4*)&x[(size_t)i * 4];
    float vv[4] = {v.x, v.y, v.z, v.w};
    f16x4 h, l;
#pragma unroll
    for (int j = 0; j < 4; ++j) {
        f16 hj = (f16)vv[j];
        h[j] = hj;
        l[j] = (f16)(vv[j] - (float)hj);
    }
    *(f16x4*)&xh[(size_t)i * 4] = h;
    *(f16x4*)&xl[(size_t)i * 4] = l;
}

__global__ void split_w_kernel(const float* __restrict__ W0, const float* __restrict__ W1,
                               const float* __restrict__ W2, f16* __restrict__ w0h,
                               f16* __restrict__ w0l, f16* __restrict__ w1h,
                               f16* __restrict__ w1l, f16* __restrict__ w2h,
                               f16* __restrict__ w2l) {
    int idx = blockIdx.x * 256 + threadIdx.x;
    if (idx < 16384) {
        int k = idx >> 7, c = idx & 127;
        float v = W0[k * 128 + c];
        f16 h = (f16)v;
        w0h[c * 128 + k] = h;
        w0l[c * 128 + k] = (f16)(v - (float)h);
    } else if (idx < 32768) {
        int t = idx - 16384;
        int k = t >> 7, c = t & 127;
        float v = W1[k * 128 + c];
        f16 h = (f16)v;
        w1h[c * 128 + k] = h;
        w1l[c * 128 + k] = (f16)(v - (float)h);
    } else if (idx < 40960) {
        int t = idx - 32768;
        int k = t >> 6, c = t & 63;
        float v = W2[k * 64 + c];
        f16 h = (f16)v;
        w2h[c * 128 + k] = h;
        w2l[c * 128 + k] = (f16)(v - (float)h);
    }
}

// ---------------- split-fp16 MFMA GEMM ----------------
template <int FOUT>
__global__ __launch_bounds__(256) void gemm_mfma_kernel(
    const f16* __restrict__ Ah, const f16* __restrict__ Al, const f16* __restrict__ Bh,
    const f16* __restrict__ Bl, f16* __restrict__ H16, int N) {
    constexpr int CT = FOUT / 16;
    __shared__ f16 lw[2][FOUT][72];
    int tid = threadIdx.x;
    int w = tid >> 6, lane = tid & 63;
    int quad = lane >> 4, m = lane & 15;
    int row0 = blockIdx.x * 64 + w * 16;
    int arow = row0 + m;
    if (arow >= N) arow = N - 1;
    const f16* aph = &Ah[(size_t)arow * 128 + quad * 8];
    const f16* apl = &Al[(size_t)arow * 128 + quad * 8];

    f32x4 acc[CT];
#pragma unroll
    for (int t = 0; t < CT; ++t) acc[t] = (f32x4){0.f, 0.f, 0.f, 0.f};

    for (int kh = 0; kh < 2; ++kh) {
        __syncthreads();
        for (int f = tid; f < FOUT * 8; f += 256) {
            int col = f >> 3, ch = f & 7;
            *(f16x8*)&lw[0][col][ch * 8] = *(const f16x8*)&Bh[(size_t)col * 128 + kh * 64 + ch * 8];
            *(f16x8*)&lw[1][col][ch * 8] = *(const f16x8*)&Bl[(size_t)col * 128 + kh * 64 + ch * 8];
        }
        __syncthreads();
#pragma unroll
        for (int kc = 0; kc < 2; ++kc) {
            f16x8 fah = *(const f16x8*)&aph[kh * 64 + kc * 32];
            f16x8 fal = *(const f16x8*)&apl[kh * 64 + kc * 32];
#pragma unroll
            for (int t = 0; t < CT; ++t) {
                f16x8 fbh = *(const f16x8*)&lw[0][t * 16 + m][kc * 32 + quad * 8];
                f16x8 fbl = *(const f16x8*)&lw[1][t * 16 + m][kc * 32 + quad * 8];
                acc[t] = __builtin_amdgcn_mfma_f32_16x16x32_f16(fah, fbh, acc[t], 0, 0, 0);
                acc[t] = __builtin_amdgcn_mfma_f32_16x16x32_f16(fal, fbh, acc[t], 0, 0, 0);
                acc[t] = __builtin_amdgcn_mfma_f32_16x16x32_f16(fah, fbl, acc[t], 0, 0, 0);
            }
        }
    }
#pragma unroll
    for (int r = 0; r < 4; ++r) {
        int row = row0 + quad * 4 + r;
        if (row < N) {
#pragma unroll
            for (int t = 0; t < CT; ++t)
                H16[(size_t)row * FOUT + t * 16 + m] = (f16)acc[t][r];
        }
    }
}

// ---------------- alpha dots ----------------
template <int H_, int C>
__global__ void alpha_kernel(const f16* __restrict__ h16, const float* __restrict__ a_src,
                             const float* __restrict__ a_dst, float* __restrict__ asrc,
                             float* __restrict__ adst, int N) {
    int idx = blockIdx.x * blockDim.x + threadIdx.x;
    if (idx >= N * H_) return;
    int n = idx / H_, h = idx % H_;
    const f16* hp = &h16[(size_t)n * H_ * C + h * C];
    const float* as = &a_src[h * C];
    const float* ad = &a_dst[h * C];
    float s1 = 0.f, s2 = 0.f;
#pragma unroll
    for (int c8 = 0; c8 < C / 8; ++c8) {
        f16x8 v = *(const f16x8*)&hp[c8 * 8];
#pragma unroll
        for (int j = 0; j < 8; ++j) {
            float vv = (float)v[j];
            s1 += vv * as[c8 * 8 + j];
            s2 += vv * ad[c8 * 8 + j];
        }
    }
    asrc[idx] = s1;
    adst[idx] = s2;
}

// ---------------- per-edge softmax weights ----------------
// w[h][k] = exp(e_k(h) - e_self(dst,h)); softmax ratio is unchanged and the
// shifted exponent is bounded (every node has a self-loop), so no max pass.
template <int H_>
__global__ void edgew_kernel(const int* __restrict__ ssrc, const float* __restrict__ asrc,
                             const float* __restrict__ adst, float* __restrict__ w, int E) {
    int k = blockIdx.x * 256 + threadIdx.x;
    if (k >= E) return;
    unsigned int rec = (unsigned int)ssrc[k];
    int s = rec & 0xFFFFu, d = rec >> 16;
    if (H_ == 4) {
        float4 a_s = *(const float4*)&asrc[s * 4];
        float4 a_dd = *(const float4*)&adst[d * 4];
        float4 a_sd = *(const float4*)&asrc[d * 4];
        w[0 * E + k] = __expf(lrelu(a_s.x + a_dd.x) - lrelu(a_sd.x + a_dd.x));
        w[1 * E + k] = __expf(lrelu(a_s.y + a_dd.y) - lrelu(a_sd.y + a_dd.y));
        w[2 * E + k] = __expf(lrelu(a_s.z + a_dd.z) - lrelu(a_sd.z + a_dd.z));
        w[3 * E + k] = __expf(lrelu(a_s.w + a_dd.w) - lrelu(a_sd.w + a_dd.w));
    } else {
        w[k] = __expf(lrelu(asrc[s] + adst[d]) - lrelu(asrc[d] + adst[d]));
    }
}

// ---------------- aggregation: D=1+sum(w), S=h_self+sum(w*h[src]) ----------------
template <int H_, int C, bool RELU, bool SPLIT_OUT>
__global__ __launch_bounds__(256) void aggr_kernel(
    const f16* __restrict__ h16, const float* __restrict__ wedge,
    const float* __restrict__ bias, const int* __restrict__ offsets,
    const int* __restrict__ ssrc, float* __restrict__ outf, f16* __restrict__ outh,
    f16* __restrict__ outl, int N, int E) {
    constexpr int FOUT = H_ * C;
    constexpr int PER = FOUT / 64;
    int wid = threadIdx.x >> 6;
    int lane = threadIdx.x & 63;
    int n = blockIdx.x * 4 + wid;
    if (n >= N) return;
    int c0 = lane * PER;
    int head = c0 / C;
    const float* wb = wedge + head * E;

    float D = 1.f;
    float S0, S1 = 0.f;
    if (PER == 2) {
        f16x2 hv = *(const f16x2*)&h16[n * FOUT + c0];
        S0 = (float)hv[0];
        S1 = (float)hv[1];
    } else {
        S0 = (float)h16[n * FOUT + c0];
    }

    int k = offsets[n];
    const int e1 = offsets[n + 1];

    // peel to 4-alignment so int4/float4 loads are aligned
    for (; k < e1 && (k & 3); ++k) {
        int s = ssrc[k] & 0xFFFF;
        float w = wb[k];
        D += w;
        if (PER == 2) {
            f16x2 hv = *(const f16x2*)&h16[s * FOUT + c0];
            S0 += w * (float)hv[0];
            S1 += w * (float)hv[1];
        } else {
            S0 += w * (float)h16[s * FOUT + c0];
        }
    }
    for (; k + 4 <= e1; k += 4) {
        int4 pk = *(const int4*)&ssrc[k];
        float4 wv = *(const float4*)&wb[k];
        int s0 = pk.x & 0xFFFF, s1 = pk.y & 0xFFFF, s2 = pk.z & 0xFFFF, s3 = pk.w & 0xFFFF;
        if (PER == 2) {
            f16x2 h0 = *(const f16x2*)&h16[s0 * FOUT + c0];
            f16x2 h1 = *(const f16x2*)&h16[s1 * FOUT + c0];
            f16x2 h2 = *(const f16x2*)&h16[s2 * FOUT + c0];
            f16x2 h3 = *(const f16x2*)&h16[s3 * FOUT + c0];
            D += (wv.x + wv.y) + (wv.z + wv.w);
            S0 += wv.x * (float)h0[0] + wv.y * (float)h1[0] + wv.z * (float)h2[0] +
                  wv.w * (float)h3[0];
            S1 += wv.x * (float)h0[1] + wv.y * (float)h1[1] + wv.z * (float)h2[1] +
                  wv.w * (float)h3[1];
        } else {
            float g0 = (float)h16[s0 * FOUT + c0];
            float g1 = (float)h16[s1 * FOUT + c0];
            float g2 = (float)h16[s2 * FOUT + c0];
            float g3 = (float)h16[s3 * FOUT + c0];
            D += (wv.x + wv.y) + (wv.z + wv.w);
            S0 += wv.x * g0 + wv.y * g1 + wv.z * g2 + wv.w * g3;
        }
    }
    for (; k < e1; ++k) {
        int s = ssrc[k] & 0xFFFF;
        float w = wb[k];
        D += w;
        if (PER == 2) {
            f16x2 hv = *(const f16x2*)&h16[s * FOUT + c0];
            S0 += w * (float)hv[0];
            S1 += w * (float)hv[1];
        } else {
            S0 += w * (float)h16[s * FOUT + c0];
        }
    }

    float inv = 1.f / (D + 1e-16f);
    float v0 = S0 * inv + bias[c0];
    if (RELU) v0 = fmaxf(v0, 0.f);
    if (SPLIT_OUT) {
        float v1 = S1 * inv + bias[c0 + 1];
        if (RELU) v1 = fmaxf(v1, 0.f);
        f16 h0 = (f16)v0, h1 = (f16)v1;
        f16x2 hh = {h0, h1};
        f16x2 ll = {(f16)(v0 - (float)h0), (f16)(v1 - (float)h1)};
        *(f16x2*)&outh[n * FOUT + c0] = hh;
        *(f16x2*)&outl[n * FOUT + c0] = ll;
    } else if (PER == 2) {
        float v1 = S1 * inv + bias[c0 + 1];
        if (RELU) v1 = fmaxf(v1, 0.f);
        *(float2*)&outf[n * FOUT + c0] = make_float2(v0, v1);
    } else {
        outf[n * FOUT + c0] = v0;
    }
}

extern "C" void kernel_launch(void* const* d_in, const int* in_sizes, int n_in,
                              void* d_out, int out_size, void* d_ws, size_t ws_size,
                              hipStream_t stream) {
    const float* x = (const float*)d_in[0];
    const int* ei = (const int*)d_in[1];
    const float* W0 = (const float*)d_in[2];
    const float* as0 = (const float*)d_in[3];
    const float* ad0 = (const float*)d_in[4];
    const float* b0 = (const float*)d_in[5];
    const float* W1 = (const float*)d_in[6];
    const float* as1 = (const float*)d_in[7];
    const float* ad1 = (const float*)d_in[8];
    const float* b1 = (const float*)d_in[9];
    const float* W2 = (const float*)d_in[10];
    const float* as2 = (const float*)d_in[11];
    const float* ad2 = (const float*)d_in[12];
    const float* b2 = (const float*)d_in[13];

    const int N = in_sizes[0] / 128;   // 50000
    const int E = in_sizes[1] / 2;     // 800000
    const int NBK = (N + 255) >> 8;    // 196 coarse buckets (N < 65536)

    // workspace carve (all 16B-aligned)
    float* aS = (float*)d_ws;                  // N*4 f32
    float* aD = aS + (size_t)N * 4;            // N*4 f32
    f16* h16 = (f16*)(aD + (size_t)N * 4);     // N*128 f16
    f16* xh = h16 + (size_t)N * 128;           // N*128 f16
    f16* xl = xh + (size_t)N * 128;            // N*128 f16
    f16* w0h = xl + (size_t)N * 128;           // 128*128
    f16* w0l = w0h + 16384;
    f16* w1h = w0l + 16384;
    f16* w1l = w1h + 16384;
    f16* w2h = w1l + 16384;                    // 64*128
    f16* w2l = w2h + 8192;
    int* offsets = (int*)(w2l + 8192);         // N+1
    int* ssrc = offsets + N + 1;               // E (packed src|dst<<16)
    unsigned int* staging = (unsigned int*)(ssrc + E);  // E
    float* wedge = (float*)(staging + E);      // E*4 f32
    int* bcount = (int*)(wedge + (size_t)E * 4);  // NBK
    int* bbase = bcount + NBK;                 // NBK+1
    int* bcursor = bbase + NBK + 1;            // NBK

    // ---- CSR build ----
    fill_zero_kernel<<<1, 256, 0, stream>>>(bcount, NBK);
    bucket_count_kernel<<<196, 256, 0, stream>>>(ei + E, E, bcount);
    bucket_scan_kernel<<<1, 256, 0, stream>>>(bcount, NBK, bbase, bcursor, offsets, N);
    bucket_scatter_kernel<<<(E + SC_TILE - 1) / SC_TILE, 256, 0, stream>>>(ei, ei + E, E, bcursor,
                                                                           staging);
    bucket_sort_kernel<<<NBK, 256, 0, stream>>>(staging, bbase, offsets, ssrc, N);

    // ---- splits ----
    split_x_kernel<<<(N * 32 + 255) / 256, 256, 0, stream>>>(x, xh, xl, N * 32);
    split_w_kernel<<<160, 256, 0, stream>>>(W0, W1, W2, w0h, w0l, w1h, w1l, w2h, w2l);

    const int gGemm = (N + 63) / 64;
    const int gAggr = (N + 3) / 4;
    const int gE = (E + 255) / 256;

    // ---- layer 0 ----
    gemm_mfma_kernel<128><<<gGemm, 256, 0, stream>>>(xh, xl, w0h, w0l, h16, N);
    alpha_kernel<4, 32><<<(N * 4 + 255) / 256, 256, 0, stream>>>(h16, as0, ad0, aS, aD, N);
    edgew_kernel<4><<<gE, 256, 0, stream>>>(ssrc, aS, aD, wedge, E);
    aggr_kernel<4, 32, true, true><<<gAggr, 256, 0, stream>>>(h16, wedge, b0, offsets, ssrc,
                                                              nullptr, xh, xl, N, E);
    // ---- layer 1 ----
    gemm_mfma_kernel<128><<<gGemm, 256, 0, stream>>>(xh, xl, w1h, w1l, h16, N);
    alpha_kernel<4, 32><<<(N * 4 + 255) / 256, 256, 0, stream>>>(h16, as1, ad1, aS, aD, N);
    edgew_kernel<4><<<gE, 256, 0, stream>>>(ssrc, aS, aD, wedge, E);
    aggr_kernel<4, 32, true, true><<<gAggr, 256, 0, stream>>>(h16, wedge, b1, offsets, ssrc,
                                                              nullptr, xh, xl, N, E);
    // ---- layer 2 ----
    gemm_mfma_kernel<64><<<gGemm, 256, 0, stream>>>(xh, xl, w2h, w2l, h16, N);
    alpha_kernel<1, 64><<<(N + 255) / 256, 256, 0, stream>>>(h16, as2, ad2, aS, aD, N);
    edgew_kernel<1><<<gE, 256, 0, stream>>>(ssrc, aS, aD, wedge, E);
    aggr_kernel<1, 64, false, false><<<gAggr, 256, 0, stream>>>(h16, wedge, b2, offsets, ssrc,
                                                                (float*)d_out, nullptr, nullptr,
                                                                N, E);
}

// Round 7
// 320.992 us; speedup vs baseline: 1.0862x; 1.0862x over previous
//
#include <hip/hip_runtime.h>

// GAT encoder, 3 layers. N=50000, E=800000, Fin=128.
// R6 -> R7: aggr_kernel restructured for memory-level parallelism.
// Wave = GROUPS lane-groups; each group gathers a DIFFERENT edge's full h-row
// (lane loads f16x8), unrolled -> 16 independent row-gathers in flight/wave
// (was 4). Group partials combined by shfl_xor butterfly (weights are
// precomputed per edge, aggregation is a pure linear sum). wedge is AoS [E][4].

#define NEG_SLOPE 0.2f

typedef _Float16 f16;
typedef f16 f16x8 __attribute__((ext_vector_type(8)));
typedef f16 f16x4 __attribute__((ext_vector_type(4)));
typedef f16 f16x2 __attribute__((ext_vector_type(2)));
typedef float f32x4 __attribute__((ext_vector_type(4)));

__device__ __forceinline__ float lrelu(float v) { return v > 0.f ? v : NEG_SLOPE * v; }

// ---------------- CSR build: two-level counting sort ----------------

__global__ void fill_zero_kernel(int* __restrict__ p, int n) {
    int i = blockIdx.x * blockDim.x + threadIdx.x;
    if (i < n) p[i] = 0;
}

__global__ __launch_bounds__(256) void bucket_count_kernel(const int* __restrict__ dst, int E,
                                                           int* __restrict__ bcount) {
    __shared__ int lh[256];
    lh[threadIdx.x] = 0;
    __syncthreads();
    int stride = gridDim.x * 256 * 4;
    for (int i = (blockIdx.x * 256 + threadIdx.x) * 4; i < E; i += stride) {
        int4 d = *(const int4*)&dst[i];
        atomicAdd(&lh[d.x >> 8], 1);
        atomicAdd(&lh[d.y >> 8], 1);
        atomicAdd(&lh[d.z >> 8], 1);
        atomicAdd(&lh[d.w >> 8], 1);
    }
    __syncthreads();
    int v = lh[threadIdx.x];
    if (v > 0) atomicAdd(&bcount[threadIdx.x], v);
}

__global__ __launch_bounds__(256) void bucket_scan_kernel(const int* __restrict__ bcount, int NBK,
                                                          int* __restrict__ bbase,
                                                          int* __restrict__ bcursor,
                                                          int* __restrict__ offsets, int N) {
    int t = threadIdx.x;
    int own = (t < NBK) ? bcount[t] : 0;
    int v = own;
    int lane = t & 63, wid = t >> 6;
#pragma unroll
    for (int off = 1; off < 64; off <<= 1) {
        int u = __shfl_up(v, off);
        if (lane >= off) v += u;
    }
    __shared__ int ws[4];
    if (lane == 63) ws[wid] = v;
    __syncthreads();
    int add = 0;
    for (int w = 0; w < wid; ++w) add += ws[w];
    v += add;
    int exc = v - own;
    if (t < NBK) {
        bbase[t] = exc;
        bcursor[t] = exc;
    }
    if (t == 255) {
        bbase[NBK] = v;
        offsets[N] = v;
    }
}

#define SC_TILE 4096
__global__ __launch_bounds__(256) void bucket_scatter_kernel(const int* __restrict__ src,
                                                             const int* __restrict__ dst, int E,
                                                             int* __restrict__ bcursor,
                                                             unsigned int* __restrict__ staging) {
    __shared__ int lh[256];
    __shared__ int lcur[256];
    int tid = threadIdx.x;
    lh[tid] = 0;
    __syncthreads();
    int base = blockIdx.x * SC_TILE + tid * 16;
    int sv[16], dv[16];
    bool act = base < E;
    if (act) {
#pragma unroll
        for (int q = 0; q < 4; ++q) {
            *(int4*)&sv[q * 4] = *(const int4*)&src[base + q * 4];
            *(int4*)&dv[q * 4] = *(const int4*)&dst[base + q * 4];
        }
#pragma unroll
        for (int j = 0; j < 16; ++j) atomicAdd(&lh[dv[j] >> 8], 1);
    }
    __syncthreads();
    int c = lh[tid];
    if (c > 0) lcur[tid] = atomicAdd(&bcursor[tid], c);
    __syncthreads();
    if (act) {
#pragma unroll
        for (int j = 0; j < 16; ++j) {
            int b = dv[j] >> 8;
            int pos = atomicAdd(&lcur[b], 1);
            staging[pos] = (unsigned int)sv[j] | ((unsigned int)(dv[j] & 255) << 16);
        }
    }
}

__global__ __launch_bounds__(256) void bucket_sort_kernel(const unsigned int* __restrict__ staging,
                                                          const int* __restrict__ bbase,
                                                          int* __restrict__ offsets,
                                                          int* __restrict__ ssrc, int N) {
    __shared__ int lh[256];
    __shared__ int ws[4];
    int b = blockIdx.x;
    int tid = threadIdx.x;
    int s = bbase[b], e = bbase[b + 1];
    int cnt = e - s;
    lh[tid] = 0;
    __syncthreads();
    for (int i = tid; i < cnt; i += 256) atomicAdd(&lh[staging[s + i] >> 16], 1);
    __syncthreads();
    int own = lh[tid];
    int v = own;
    int lane = tid & 63, wid = tid >> 6;
#pragma unroll
    for (int off = 1; off < 64; off <<= 1) {
        int u = __shfl_up(v, off);
        if (lane >= off) v += u;
    }
    if (lane == 63) ws[wid] = v;
    __syncthreads();
    int add = 0;
    for (int w = 0; w < wid; ++w) add += ws[w];
    int exc = v + add - own;
    int dstn = (b << 8) + tid;
    if (dstn < N) offsets[dstn] = s + exc;
    __syncthreads();
    lh[tid] = exc;
    __syncthreads();
    for (int i = tid; i < cnt; i += 256) {
        unsigned int rec = staging[s + i];
        int dlow = rec >> 16;
        int r = atomicAdd(&lh[dlow], 1);
        unsigned int full = (rec & 0xFFFFu) | ((unsigned int)((b << 8) | dlow) << 16);
        ssrc[s + r] = (int)full;
    }
}

// ---------------- fp16 splits ----------------

__global__ void split_x_kernel(const float* __restrict__ x, f16* __restrict__ xh,
                               f16* __restrict__ xl, int total4) {
    int i = blockIdx.x * blockDim.x + threadIdx.x;
    if (i >= total4) return;
    float4 v = *(const float4*)&x[(size_t)i * 4];
    float vv[4] = {v.x, v.y, v.z, v.w};
    f16x4 h, l;
#pragma unroll
    for (int j = 0; j < 4; ++j) {
        f16 hj = (f16)vv[j];
        h[j] = hj;
        l[j] = (f16)(vv[j] - (float)hj);
    }
    *(f16x4*)&xh[(size_t)i * 4] = h;
    *(f16x4*)&xl[(size_t)i * 4] = l;
}

__global__ void split_w_kernel(const float* __restrict__ W0, const float* __restrict__ W1,
                               const float* __restrict__ W2, f16* __restrict__ w0h,
                               f16* __restrict__ w0l, f16* __restrict__ w1h,
                               f16* __restrict__ w1l, f16* __restrict__ w2h,
                               f16* __restrict__ w2l) {
    int idx = blockIdx.x * 256 + threadIdx.x;
    if (idx < 16384) {
        int k = idx >> 7, c = idx & 127;
        float v = W0[k * 128 + c];
        f16 h = (f16)v;
        w0h[c * 128 + k] = h;
        w0l[c * 128 + k] = (f16)(v - (float)h);
    } else if (idx < 32768) {
        int t = idx - 16384;
        int k = t >> 7, c = t & 127;
        float v = W1[k * 128 + c];
        f16 h = (f16)v;
        w1h[c * 128 + k] = h;
        w1l[c * 128 + k] = (f16)(v - (float)h);
    } else if (idx < 40960) {
        int t = idx - 32768;
        int k = t >> 6, c = t & 63;
        float v = W2[k * 64 + c];
        f16 h = (f16)v;
        w2h[c * 128 + k] = h;
        w2l[c * 128 + k] = (f16)(v - (float)h);
    }
}

// ---------------- split-fp16 MFMA GEMM ----------------
template <int FOUT>
__global__ __launch_bounds__(256) void gemm_mfma_kernel(
    const f16* __restrict__ Ah, const f16* __restrict__ Al, const f16* __restrict__ Bh,
    const f16* __restrict__ Bl, f16* __restrict__ H16, int N) {
    constexpr int CT = FOUT / 16;
    __shared__ f16 lw[2][FOUT][72];
    int tid = threadIdx.x;
    int w = tid >> 6, lane = tid & 63;
    int quad = lane >> 4, m = lane & 15;
    int row0 = blockIdx.x * 64 + w * 16;
    int arow = row0 + m;
    if (arow >= N) arow = N - 1;
    const f16* aph = &Ah[(size_t)arow * 128 + quad * 8];
    const f16* apl = &Al[(size_t)arow * 128 + quad * 8];

    f32x4 acc[CT];
#pragma unroll
    for (int t = 0; t < CT; ++t) acc[t] = (f32x4){0.f, 0.f, 0.f, 0.f};

    for (int kh = 0; kh < 2; ++kh) {
        __syncthreads();
        for (int f = tid; f < FOUT * 8; f += 256) {
            int col = f >> 3, ch = f & 7;
            *(f16x8*)&lw[0][col][ch * 8] = *(const f16x8*)&Bh[(size_t)col * 128 + kh * 64 + ch * 8];
            *(f16x8*)&lw[1][col][ch * 8] = *(const f16x8*)&Bl[(size_t)col * 128 + kh * 64 + ch * 8];
        }
        __syncthreads();
#pragma unroll
        for (int kc = 0; kc < 2; ++kc) {
            f16x8 fah = *(const f16x8*)&aph[kh * 64 + kc * 32];
            f16x8 fal = *(const f16x8*)&apl[kh * 64 + kc * 32];
#pragma unroll
            for (int t = 0; t < CT; ++t) {
                f16x8 fbh = *(const f16x8*)&lw[0][t * 16 + m][kc * 32 + quad * 8];
                f16x8 fbl = *(const f16x8*)&lw[1][t * 16 + m][kc * 32 + quad * 8];
                acc[t] = __builtin_amdgcn_mfma_f32_16x16x32_f16(fah, fbh, acc[t], 0, 0, 0);
                acc[t] = __builtin_amdgcn_mfma_f32_16x16x32_f16(fal, fbh, acc[t], 0, 0, 0);
                acc[t] = __builtin_amdgcn_mfma_f32_16x16x32_f16(fah, fbl, acc[t], 0, 0, 0);
            }
        }
    }
#pragma unroll
    for (int r = 0; r < 4; ++r) {
        int row = row0 + quad * 4 + r;
        if (row < N) {
#pragma unroll
            for (int t = 0; t < CT; ++t)
                H16[(size_t)row * FOUT + t * 16 + m] = (f16)acc[t][r];
        }
    }
}

// ---------------- alpha dots ----------------
template <int H_, int C>
__global__ void alpha_kernel(const f16* __restrict__ h16, const float* __restrict__ a_src,
                             const float* __restrict__ a_dst, float* __restrict__ asrc,
                             float* __restrict__ adst, int N) {
    int idx = blockIdx.x * blockDim.x + threadIdx.x;
    if (idx >= N * H_) return;
    int n = idx / H_, h = idx % H_;
    const f16* hp = &h16[(size_t)n * H_ * C + h * C];
    const float* as = &a_src[h * C];
    const float* ad = &a_dst[h * C];
    float s1 = 0.f, s2 = 0.f;
#pragma unroll
    for (int c8 = 0; c8 < C / 8; ++c8) {
        f16x8 v = *(const f16x8*)&hp[c8 * 8];
#pragma unroll
        for (int j = 0; j < 8; ++j) {
            float vv = (float)v[j];
            s1 += vv * as[c8 * 8 + j];
            s2 += vv * ad[c8 * 8 + j];
        }
    }
    asrc[idx] = s1;
    adst[idx] = s2;
}

// ---------------- per-edge softmax weights ----------------
// H=4: AoS [E][4] (one 16B line per edge). H=1: scalar [E].
template <int H_>
__global__ void edgew_kernel(const int* __restrict__ ssrc, const float* __restrict__ asrc,
                             const float* __restrict__ adst, float* __restrict__ w, int E) {
    int k = blockIdx.x * 256 + threadIdx.x;
    if (k >= E) return;
    unsigned int rec = (unsigned int)ssrc[k];
    int s = rec & 0xFFFFu, d = rec >> 16;
    if (H_ == 4) {
        float4 a_s = *(const float4*)&asrc[s * 4];
        float4 a_dd = *(const float4*)&adst[d * 4];
        float4 a_sd = *(const float4*)&asrc[d * 4];
        float4 o;
        o.x = __expf(lrelu(a_s.x + a_dd.x) - lrelu(a_sd.x + a_dd.x));
        o.y = __expf(lrelu(a_s.y + a_dd.y) - lrelu(a_sd.y + a_dd.y));
        o.z = __expf(lrelu(a_s.z + a_dd.z) - lrelu(a_sd.z + a_dd.z));
        o.w = __expf(lrelu(a_s.w + a_dd.w) - lrelu(a_sd.w + a_dd.w));
        *(float4*)&w[(size_t)k * 4] = o;
    } else {
        w[k] = __expf(lrelu(asrc[s] + adst[d]) - lrelu(asrc[d] + adst[d]));
    }
}

// ---------------- aggregation: group-per-edge MLP ----------------
// Wave = GROUPS groups of LPG lanes; group g gathers edge e0+g, e0+g+GROUPS,...
// Each lane owns 8 channels (f16x8). Partials merged via shfl_xor butterfly.
template <int H_, int C, bool RELU, bool SPLIT_OUT>
__global__ __launch_bounds__(256) void aggr_kernel(
    const f16* __restrict__ h16, const float* __restrict__ wedge,
    const float* __restrict__ bias, const int* __restrict__ offsets,
    const int* __restrict__ ssrc, float* __restrict__ outf, f16* __restrict__ outh,
    f16* __restrict__ outl, int N) {
    constexpr int FOUT = H_ * C;        // 128 or 64
    constexpr int LPG = FOUT / 8;       // lanes per group: 16 or 8
    constexpr int GROUPS = 64 / LPG;    // 4 or 8
    constexpr int UN = (GROUPS == 4) ? 4 : 2;  // 16 rows in flight per wave
    int wid = threadIdx.x >> 6;
    int lane = threadIdx.x & 63;
    int n = blockIdx.x * 4 + wid;
    if (n >= N) return;
    int g = lane / LPG;
    int t = lane % LPG;
    int c0 = t * 8;
    int head = c0 / C;

    float D = 0.f;
    float S[8];
#pragma unroll
    for (int j = 0; j < 8; ++j) S[j] = 0.f;
    if (g == 0) {  // self-loop (w = 1) counted once
        D = 1.f;
        f16x8 hv = *(const f16x8*)&h16[n * FOUT + c0];
#pragma unroll
        for (int j = 0; j < 8; ++j) S[j] = (float)hv[j];
    }

    int e1 = offsets[n + 1];
    int k = offsets[n] + g;

    for (; k + (UN - 1) * GROUPS < e1; k += UN * GROUPS) {
        float wv[UN];
        f16x8 hvv[UN];
#pragma unroll
        for (int u = 0; u < UN; ++u) {
            int kk = k + u * GROUPS;
            int s = ssrc[kk] & 0xFFFF;
            wv[u] = (H_ == 4) ? wedge[(size_t)kk * 4 + head] : wedge[kk];
            hvv[u] = *(const f16x8*)&h16[s * FOUT + c0];
        }
#pragma unroll
        for (int u = 0; u < UN; ++u) {
            D += wv[u];
#pragma unroll
            for (int j = 0; j < 8; ++j) S[j] += wv[u] * (float)hvv[u][j];
        }
    }
    for (; k < e1; k += GROUPS) {
        int s = ssrc[k] & 0xFFFF;
        float w = (H_ == 4) ? wedge[(size_t)k * 4 + head] : wedge[k];
        f16x8 hv = *(const f16x8*)&h16[s * FOUT + c0];
        D += w;
#pragma unroll
        for (int j = 0; j < 8; ++j) S[j] += w * (float)hv[j];
    }

    // merge group partials (uniform control flow within the wave)
#pragma unroll
    for (int mask = LPG; mask < 64; mask <<= 1) {
        D += __shfl_xor(D, mask);
#pragma unroll
        for (int j = 0; j < 8; ++j) S[j] += __shfl_xor(S[j], mask);
    }

    if (g == 0) {
        float inv = 1.f / (D + 1e-16f);
        float v[8];
#pragma unroll
        for (int j = 0; j < 8; ++j) {
            v[j] = S[j] * inv + bias[c0 + j];
            if (RELU) v[j] = fmaxf(v[j], 0.f);
        }
        if (SPLIT_OUT) {
            f16x8 hh, ll;
#pragma unroll
            for (int j = 0; j < 8; ++j) {
                f16 h = (f16)v[j];
                hh[j] = h;
                ll[j] = (f16)(v[j] - (float)h);
            }
            *(f16x8*)&outh[n * FOUT + c0] = hh;
            *(f16x8*)&outl[n * FOUT + c0] = ll;
        } else {
            *(float4*)&outf[n * FOUT + c0] = make_float4(v[0], v[1], v[2], v[3]);
            *(float4*)&outf[n * FOUT + c0 + 4] = make_float4(v[4], v[5], v[6], v[7]);
        }
    }
}

extern "C" void kernel_launch(void* const* d_in, const int* in_sizes, int n_in,
                              void* d_out, int out_size, void* d_ws, size_t ws_size,
                              hipStream_t stream) {
    const float* x = (const float*)d_in[0];
    const int* ei = (const int*)d_in[1];
    const float* W0 = (const float*)d_in[2];
    const float* as0 = (const float*)d_in[3];
    const float* ad0 = (const float*)d_in[4];
    const float* b0 = (const float*)d_in[5];
    const float* W1 = (const float*)d_in[6];
    const float* as1 = (const float*)d_in[7];
    const float* ad1 = (const float*)d_in[8];
    const float* b1 = (const float*)d_in[9];
    const float* W2 = (const float*)d_in[10];
    const float* as2 = (const float*)d_in[11];
    const float* ad2 = (const float*)d_in[12];
    const float* b2 = (const float*)d_in[13];

    const int N = in_sizes[0] / 128;   // 50000
    const int E = in_sizes[1] / 2;     // 800000
    const int NBK = (N + 255) >> 8;    // 196 coarse buckets (N < 65536)

    // workspace carve (all 16B-aligned)
    float* aS = (float*)d_ws;                  // N*4 f32
    float* aD = aS + (size_t)N * 4;            // N*4 f32
    f16* h16 = (f16*)(aD + (size_t)N * 4);     // N*128 f16
    f16* xh = h16 + (size_t)N * 128;           // N*128 f16
    f16* xl = xh + (size_t)N * 128;            // N*128 f16
    f16* w0h = xl + (size_t)N * 128;           // 128*128
    f16* w0l = w0h + 16384;
    f16* w1h = w0l + 16384;
    f16* w1l = w1h + 16384;
    f16* w2h = w1l + 16384;                    // 64*128
    f16* w2l = w2h + 8192;
    int* offsets = (int*)(w2l + 8192);         // N+1
    int* ssrc = offsets + N + 1;               // E (packed src|dst<<16)
    unsigned int* staging = (unsigned int*)(ssrc + E);  // E
    float* wedge = (float*)(staging + E);      // E*4 f32 (AoS for H=4)
    int* bcount = (int*)(wedge + (size_t)E * 4);  // NBK
    int* bbase = bcount + NBK;                 // NBK+1
    int* bcursor = bbase + NBK + 1;            // NBK

    // ---- CSR build ----
    fill_zero_kernel<<<1, 256, 0, stream>>>(bcount, NBK);
    bucket_count_kernel<<<196, 256, 0, stream>>>(ei + E, E, bcount);
    bucket_scan_kernel<<<1, 256, 0, stream>>>(bcount, NBK, bbase, bcursor, offsets, N);
    bucket_scatter_kernel<<<(E + SC_TILE - 1) / SC_TILE, 256, 0, stream>>>(ei, ei + E, E, bcursor,
                                                                           staging);
    bucket_sort_kernel<<<NBK, 256, 0, stream>>>(staging, bbase, offsets, ssrc, N);

    // ---- splits ----
    split_x_kernel<<<(N * 32 + 255) / 256, 256, 0, stream>>>(x, xh, xl, N * 32);
    split_w_kernel<<<160, 256, 0, stream>>>(W0, W1, W2, w0h, w0l, w1h, w1l, w2h, w2l);

    const int gGemm = (N + 63) / 64;
    const int gAggr = (N + 3) / 4;
    const int gE = (E + 255) / 256;

    // ---- layer 0 ----
    gemm_mfma_kernel<128><<<gGemm, 256, 0, stream>>>(xh, xl, w0h, w0l, h16, N);
    alpha_kernel<4, 32><<<(N * 4 + 255) / 256, 256, 0, stream>>>(h16, as0, ad0, aS, aD, N);
    edgew_kernel<4><<<gE, 256, 0, stream>>>(ssrc, aS, aD, wedge, E);
    aggr_kernel<4, 32, true, true><<<gAggr, 256, 0, stream>>>(h16, wedge, b0, offsets, ssrc,
                                                              nullptr, xh, xl, N);
    // ---- layer 1 ----
    gemm_mfma_kernel<128><<<gGemm, 256, 0, stream>>>(xh, xl, w1h, w1l, h16, N);
    alpha_kernel<4, 32><<<(N * 4 + 255) / 256, 256, 0, stream>>>(h16, as1, ad1, aS, aD, N);
    edgew_kernel<4><<<gE, 256, 0, stream>>>(ssrc, aS, aD, wedge, E);
    aggr_kernel<4, 32, true, true><<<gAggr, 256, 0, stream>>>(h16, wedge, b1, offsets, ssrc,
                                                              nullptr, xh, xl, N);
    // ---- layer 2 ----
    gemm_mfma_kernel<64><<<gGemm, 256, 0, stream>>>(xh, xl, w2h, w2l, h16, N);
    alpha_kernel<1, 64><<<(N + 255) / 256, 256, 0, stream>>>(h16, as2, ad2, aS, aD, N);
    edgew_kernel<1><<<gE, 256, 0, stream>>>(ssrc, aS, aD, wedge, E);
    aggr_kernel<1, 64, false, false><<<gAggr, 256, 0, stream>>>(h16, wedge, b2, offsets, ssrc,
                                                                (float*)d_out, nullptr, nullptr,
                                                                N);
}

// Round 9
// 318.246 us; speedup vs baseline: 1.0956x; 1.0086x over previous
//
#include <hip/hip_runtime.h>

// GAT encoder, 3 layers. N=50000, E=800000, Fin=128.
// R8 -> R9 (fix round):
//  * bucket_sort rewritten as a STABLE 6x4-bit LSD radix sort per bucket
//    (per-thread sequential chunks + deterministic matrix-scan cursors, no
//    atomic ranks) -> ssrc is bit-deterministic across launches. This fixes
//    the R8 tripwire (launch vs graph divergence from atomic-order FP sums).
//  * gemm epilogue alpha computed from fp16-ROUNDED acc (matches R7 numerics,
//    absmax margin restored) while keeping the R8 fusions (13 launches).

#define NEG_SLOPE 0.2f

typedef _Float16 f16;
typedef f16 f16x8 __attribute__((ext_vector_type(8)));
typedef f16 f16x4 __attribute__((ext_vector_type(4)));
typedef f16 f16x2 __attribute__((ext_vector_type(2)));
typedef float f32x4 __attribute__((ext_vector_type(4)));

__device__ __forceinline__ float lrelu(float v) { return v > 0.f ? v : NEG_SLOPE * v; }

// ---------------- CSR build: two-level counting sort ----------------

__global__ void fill_zero_kernel(int* __restrict__ p, int n) {
    int i = blockIdx.x * blockDim.x + threadIdx.x;
    if (i < n) p[i] = 0;
}

__global__ __launch_bounds__(256) void bucket_count_kernel(const int* __restrict__ dst, int E,
                                                           int* __restrict__ bcount) {
    __shared__ int lh[256];
    lh[threadIdx.x] = 0;
    __syncthreads();
    int stride = gridDim.x * 256 * 4;
    for (int i = (blockIdx.x * 256 + threadIdx.x) * 4; i < E; i += stride) {
        int4 d = *(const int4*)&dst[i];
        atomicAdd(&lh[d.x >> 8], 1);
        atomicAdd(&lh[d.y >> 8], 1);
        atomicAdd(&lh[d.z >> 8], 1);
        atomicAdd(&lh[d.w >> 8], 1);
    }
    __syncthreads();
    int v = lh[threadIdx.x];
    if (v > 0) atomicAdd(&bcount[threadIdx.x], v);
}

__global__ __launch_bounds__(256) void bucket_scan_kernel(const int* __restrict__ bcount, int NBK,
                                                          int* __restrict__ bbase,
                                                          int* __restrict__ bcursor,
                                                          int* __restrict__ offsets, int N) {
    int t = threadIdx.x;
    int own = (t < NBK) ? bcount[t] : 0;
    int v = own;
    int lane = t & 63, wid = t >> 6;
#pragma unroll
    for (int off = 1; off < 64; off <<= 1) {
        int u = __shfl_up(v, off);
        if (lane >= off) v += u;
    }
    __shared__ int ws[4];
    if (lane == 63) ws[wid] = v;
    __syncthreads();
    int add = 0;
    for (int w = 0; w < wid; ++w) add += ws[w];
    v += add;
    int exc = v - own;
    if (t < NBK) {
        bbase[t] = exc;
        bcursor[t] = exc;
    }
    if (t == 255) {
        bbase[NBK] = v;
        offsets[N] = v;
    }
}

#define SC_TILE 4096
__global__ __launch_bounds__(256) void bucket_scatter_kernel(const int* __restrict__ src,
                                                             const int* __restrict__ dst, int E,
                                                             int* __restrict__ bcursor,
                                                             unsigned int* __restrict__ staging) {
    __shared__ int lh[256];
    __shared__ int lcur[256];
    int tid = threadIdx.x;
    lh[tid] = 0;
    __syncthreads();
    int base = blockIdx.x * SC_TILE + tid * 16;
    int sv[16], dv[16];
    bool act = base < E;
    if (act) {
#pragma unroll
        for (int q = 0; q < 4; ++q) {
            *(int4*)&sv[q * 4] = *(const int4*)&src[base + q * 4];
            *(int4*)&dv[q * 4] = *(const int4*)&dst[base + q * 4];
        }
#pragma unroll
        for (int j = 0; j < 16; ++j) atomicAdd(&lh[dv[j] >> 8], 1);
    }
    __syncthreads();
    int c = lh[tid];
    if (c > 0) lcur[tid] = atomicAdd(&bcursor[tid], c);
    __syncthreads();
    if (act) {
#pragma unroll
        for (int j = 0; j < 16; ++j) {
            int b = dv[j] >> 8;
            int pos = atomicAdd(&lcur[b], 1);
            staging[pos] = (unsigned int)sv[j] | ((unsigned int)(dv[j] & 255) << 16);
        }
    }
}

// One block per bucket. Deterministic stable LSD radix sort (6 x 4-bit) of the
// bucket's records by key (dlow<<16 | src); identical keys are identical
// records, so ssrc is bit-deterministic. offsets from order-independent hist.
#define SORT_CAP 8192
#define MIDX(f) ((f) + ((f) >> 4))  // pad 1 per 16 to break LDS bank aliasing
__global__ __launch_bounds__(256) void bucket_sort_kernel(const unsigned int* __restrict__ staging,
                                                          const int* __restrict__ bbase,
                                                          int* __restrict__ offsets,
                                                          int* __restrict__ ssrc, int N) {
    __shared__ unsigned int bufA[SORT_CAP];
    __shared__ unsigned int bufB[SORT_CAP];
    __shared__ int mat[4096 + 256];
    __shared__ int lh[256];
    __shared__ int wsum[4];
    int b = blockIdx.x;
    int tid = threadIdx.x;
    int s = bbase[b], e = bbase[b + 1];
    int cnt = e - s;
    bool fits = cnt <= SORT_CAP;

    // ---- per-dlow counts (order-independent) -> offsets ----
    lh[tid] = 0;
    __syncthreads();
    if (fits) {
        for (int i = tid; i < cnt; i += 256) {
            unsigned int r = staging[s + i];
            bufA[i] = r;
            atomicAdd(&lh[r >> 16], 1);
        }
    } else {
        for (int i = tid; i < cnt; i += 256) atomicAdd(&lh[staging[s + i] >> 16], 1);
    }
    __syncthreads();
    int own = lh[tid];
    int v = own;
    int lane = tid & 63, wid = tid >> 6;
#pragma unroll
    for (int off = 1; off < 64; off <<= 1) {
        int u = __shfl_up(v, off);
        if (lane >= off) v += u;
    }
    if (lane == 63) wsum[wid] = v;
    __syncthreads();
    int add = 0;
    for (int w = 0; w < wid; ++w) add += wsum[w];
    int exc = v + add - own;
    int dstn = (b << 8) + tid;
    if (dstn < N) offsets[dstn] = s + exc;
    __syncthreads();

    if (fits) {
        // ---- stable radix sort, 6 passes x 4 bits over bits [0,24) ----
        unsigned int* in = bufA;
        unsigned int* out = bufB;
        int L = (cnt + 255) >> 8;
        int i0 = tid * L;
        int i1 = i0 + L;
        if (i0 > cnt) i0 = cnt;
        if (i1 > cnt) i1 = cnt;
        for (int sh = 0; sh < 24; sh += 4) {
            int c16[16];
#pragma unroll
            for (int d = 0; d < 16; ++d) c16[d] = 0;
            for (int i = i0; i < i1; ++i) c16[(in[i] >> sh) & 15]++;
#pragma unroll
            for (int d = 0; d < 16; ++d) mat[MIDX(d * 256 + tid)] = c16[d];
            __syncthreads();
            // exclusive scan of the 4096 flat counts (digit-major, thread-minor)
            int base = tid * 16;
            int loc[16];
            int ssum = 0;
#pragma unroll
            for (int j = 0; j < 16; ++j) {
                loc[j] = ssum;
                ssum += mat[MIDX(base + j)];
            }
            int vv = ssum;
#pragma unroll
            for (int off = 1; off < 64; off <<= 1) {
                int u = __shfl_up(vv, off);
                if (lane >= off) vv += u;
            }
            if (lane == 63) wsum[wid] = vv;
            __syncthreads();
            int add2 = 0;
            for (int w = 0; w < wid; ++w) add2 += wsum[w];
            int exc2 = vv + add2 - ssum;
#pragma unroll
            for (int j = 0; j < 16; ++j) mat[MIDX(base + j)] = exc2 + loc[j];
            __syncthreads();
#pragma unroll
            for (int d = 0; d < 16; ++d) c16[d] = mat[MIDX(d * 256 + tid)];
            // stable scatter: threads own contiguous input chunks, sequential order
            for (int i = i0; i < i1; ++i) {
                unsigned int r = in[i];
                int d = (r >> sh) & 15;
                out[c16[d]++] = r;
            }
            __syncthreads();
            unsigned int* tmp = in;
            in = out;
            out = tmp;
        }
        // 6 swaps -> sorted data in bufA
        for (int i = tid; i < cnt; i += 256) {
            unsigned int r = bufA[i];
            int dlow = (r >> 16) & 255;
            unsigned int full = (r & 0xFFFFu) | ((unsigned int)((b << 8) | dlow) << 16);
            ssrc[s + i] = (int)full;
        }
    } else {
        // fallback (cnt > SORT_CAP; statistically never at E/NBK ~ 4k)
        lh[tid] = exc;
        __syncthreads();
        for (int i = tid; i < cnt; i += 256) {
            unsigned int rec = staging[s + i];
            int dlow = rec >> 16;
            int r = atomicAdd(&lh[dlow], 1);
            unsigned int full = (rec & 0xFFFFu) | ((unsigned int)((b << 8) | dlow) << 16);
            ssrc[s + r] = (int)full;
        }
    }
}

// ---------------- fp16 splits ----------------

__global__ void split_x_kernel(const float* __restrict__ x, f16* __restrict__ xh,
                               f16* __restrict__ xl, int total4) {
    int i = blockIdx.x * blockDim.x + threadIdx.x;
    if (i >= total4) return;
    float4 v = *(const float4*)&x[(size_t)i * 4];
    float vv[4] = {v.x, v.y, v.z, v.w};
    f16x4 h, l;
#pragma unroll
    for (int j = 0; j < 4; ++j) {
        f16 hj = (f16)vv[j];
        h[j] = hj;
        l[j] = (f16)(vv[j] - (float)hj);
    }
    *(f16x4*)&xh[(size_t)i * 4] = h;
    *(f16x4*)&xl[(size_t)i * 4] = l;
}

__global__ void split_w_kernel(const float* __restrict__ W0, const float* __restrict__ W1,
                               const float* __restrict__ W2, f16* __restrict__ w0h,
                               f16* __restrict__ w0l, f16* __restrict__ w1h,
                               f16* __restrict__ w1l, f16* __restrict__ w2h,
                               f16* __restrict__ w2l) {
    int idx = blockIdx.x * 256 + threadIdx.x;
    if (idx < 16384) {
        int k = idx >> 7, c = idx & 127;
        float v = W0[k * 128 + c];
        f16 h = (f16)v;
        w0h[c * 128 + k] = h;
        w0l[c * 128 + k] = (f16)(v - (float)h);
    } else if (idx < 32768) {
        int t = idx - 16384;
        int k = t >> 7, c = t & 127;
        float v = W1[k * 128 + c];
        f16 h = (f16)v;
        w1h[c * 128 + k] = h;
        w1l[c * 128 + k] = (f16)(v - (float)h);
    } else if (idx < 40960) {
        int t = idx - 32768;
        int k = t >> 6, c = t & 63;
        float v = W2[k * 64 + c];
        f16 h = (f16)v;
        w2h[c * 128 + k] = h;
        w2l[c * 128 + k] = (f16)(v - (float)h);
    }
}

// ---------------- split-fp16 MFMA GEMM + fused alpha dots ----------------
// Alpha computed from fp16-ROUNDED acc (same values the aggregation reads),
// via 16-lane shfl_xor butterfly per row-quad.
template <int FOUT, int H_>
__global__ __launch_bounds__(256) void gemm_mfma_kernel(
    const f16* __restrict__ Ah, const f16* __restrict__ Al, const f16* __restrict__ Bh,
    const f16* __restrict__ Bl, const float* __restrict__ a_src, const float* __restrict__ a_dst,
    f16* __restrict__ H16, float* __restrict__ asrc, float* __restrict__ adst, int N) {
    constexpr int CT = FOUT / 16;
    constexpr int TPH = CT / H_;  // 16-col tiles per head
    __shared__ f16 lw[2][FOUT][72];
    int tid = threadIdx.x;
    int w = tid >> 6, lane = tid & 63;
    int quad = lane >> 4, m = lane & 15;
    int row0 = blockIdx.x * 64 + w * 16;
    int arow = row0 + m;
    if (arow >= N) arow = N - 1;
    const f16* aph = &Ah[(size_t)arow * 128 + quad * 8];
    const f16* apl = &Al[(size_t)arow * 128 + quad * 8];

    f32x4 acc[CT];
#pragma unroll
    for (int t = 0; t < CT; ++t) acc[t] = (f32x4){0.f, 0.f, 0.f, 0.f};

    for (int kh = 0; kh < 2; ++kh) {
        __syncthreads();
        for (int f = tid; f < FOUT * 8; f += 256) {
            int col = f >> 3, ch = f & 7;
            *(f16x8*)&lw[0][col][ch * 8] = *(const f16x8*)&Bh[(size_t)col * 128 + kh * 64 + ch * 8];
            *(f16x8*)&lw[1][col][ch * 8] = *(const f16x8*)&Bl[(size_t)col * 128 + kh * 64 + ch * 8];
        }
        __syncthreads();
#pragma unroll
        for (int kc = 0; kc < 2; ++kc) {
            f16x8 fah = *(const f16x8*)&aph[kh * 64 + kc * 32];
            f16x8 fal = *(const f16x8*)&apl[kh * 64 + kc * 32];
#pragma unroll
            for (int t = 0; t < CT; ++t) {
                f16x8 fbh = *(const f16x8*)&lw[0][t * 16 + m][kc * 32 + quad * 8];
                f16x8 fbl = *(const f16x8*)&lw[1][t * 16 + m][kc * 32 + quad * 8];
                acc[t] = __builtin_amdgcn_mfma_f32_16x16x32_f16(fah, fbh, acc[t], 0, 0, 0);
                acc[t] = __builtin_amdgcn_mfma_f32_16x16x32_f16(fal, fbh, acc[t], 0, 0, 0);
                acc[t] = __builtin_amdgcn_mfma_f32_16x16x32_f16(fah, fbl, acc[t], 0, 0, 0);
            }
        }
    }

    float asf[CT], adf[CT];
#pragma unroll
    for (int t = 0; t < CT; ++t) {
        asf[t] = a_src[t * 16 + m];
        adf[t] = a_dst[t * 16 + m];
    }

#pragma unroll
    for (int r = 0; r < 4; ++r) {
        int row = row0 + quad * 4 + r;
        f16 hq[CT];
        float hr[CT];
#pragma unroll
        for (int t = 0; t < CT; ++t) {
            hq[t] = (f16)acc[t][r];
            hr[t] = (float)hq[t];  // rounded value, same as what aggr reads
        }
        float pa[H_], pd[H_];
#pragma unroll
        for (int hh = 0; hh < H_; ++hh) {
            pa[hh] = 0.f;
            pd[hh] = 0.f;
#pragma unroll
            for (int tt = 0; tt < TPH; ++tt) {
                int t = hh * TPH + tt;
                pa[hh] += hr[t] * asf[t];
                pd[hh] += hr[t] * adf[t];
            }
        }
#pragma unroll
        for (int mask = 1; mask < 16; mask <<= 1) {
#pragma unroll
            for (int hh = 0; hh < H_; ++hh) {
                pa[hh] += __shfl_xor(pa[hh], mask);
                pd[hh] += __shfl_xor(pd[hh], mask);
            }
        }
        if (row < N) {
#pragma unroll
            for (int t = 0; t < CT; ++t) H16[(size_t)row * FOUT + t * 16 + m] = hq[t];
#pragma unroll
            for (int hh = 0; hh < H_; ++hh) {
                if (m == hh) {
                    asrc[row * H_ + hh] = pa[hh];
                    adst[row * H_ + hh] = pd[hh];
                }
            }
        }
    }
}

// ---------------- aggregation: group-per-edge MLP, inline softmax weight ----------------
template <int H_, int C, bool RELU, bool SPLIT_OUT>
__global__ __launch_bounds__(256) void aggr_kernel(
    const f16* __restrict__ h16, const float* __restrict__ asrc,
    const float* __restrict__ adst, const float* __restrict__ bias,
    const int* __restrict__ offsets, const int* __restrict__ ssrc, float* __restrict__ outf,
    f16* __restrict__ outh, f16* __restrict__ outl, int N) {
    constexpr int FOUT = H_ * C;        // 128 or 64
    constexpr int LPG = FOUT / 8;       // lanes per group: 16 or 8
    constexpr int GROUPS = 64 / LPG;    // 4 or 8
    constexpr int UN = (GROUPS == 4) ? 4 : 2;  // 16 rows in flight per wave
    int wid = threadIdx.x >> 6;
    int lane = threadIdx.x & 63;
    int n = blockIdx.x * 4 + wid;
    if (n >= N) return;
    int g = lane / LPG;
    int t = lane % LPG;
    int c0 = t * 8;
    int head = c0 / C;

    float adn = adst[n * H_ + head];
    float esf = lrelu(asrc[n * H_ + head] + adn);

    float D = 0.f;
    float S[8];
#pragma unroll
    for (int j = 0; j < 8; ++j) S[j] = 0.f;
    if (g == 0) {  // self-loop (w = 1) counted once
        D = 1.f;
        f16x8 hv = *(const f16x8*)&h16[n * FOUT + c0];
#pragma unroll
        for (int j = 0; j < 8; ++j) S[j] = (float)hv[j];
    }

    int e1 = offsets[n + 1];
    int k = offsets[n] + g;

    for (; k + (UN - 1) * GROUPS < e1; k += UN * GROUPS) {
        int sarr[UN];
        float aval[UN];
        f16x8 hvv[UN];
#pragma unroll
        for (int u = 0; u < UN; ++u) sarr[u] = ssrc[k + u * GROUPS] & 0xFFFF;
#pragma unroll
        for (int u = 0; u < UN; ++u) {
            aval[u] = asrc[sarr[u] * H_ + head];
            hvv[u] = *(const f16x8*)&h16[sarr[u] * FOUT + c0];
        }
#pragma unroll
        for (int u = 0; u < UN; ++u) {
            float w = __expf(lrelu(aval[u] + adn) - esf);
            D += w;
#pragma unroll
            for (int j = 0; j < 8; ++j) S[j] += w * (float)hvv[u][j];
        }
    }
    for (; k < e1; k += GROUPS) {
        int s = ssrc[k] & 0xFFFF;
        float w = __expf(lrelu(asrc[s * H_ + head] + adn) - esf);
        f16x8 hv = *(const f16x8*)&h16[s * FOUT + c0];
        D += w;
#pragma unroll
        for (int j = 0; j < 8; ++j) S[j] += w * (float)hv[j];
    }

#pragma unroll
    for (int mask = LPG; mask < 64; mask <<= 1) {
        D += __shfl_xor(D, mask);
#pragma unroll
        for (int j = 0; j < 8; ++j) S[j] += __shfl_xor(S[j], mask);
    }

    if (g == 0) {
        float inv = 1.f / (D + 1e-16f);
        float v[8];
#pragma unroll
        for (int j = 0; j < 8; ++j) {
            v[j] = S[j] * inv + bias[c0 + j];
            if (RELU) v[j] = fmaxf(v[j], 0.f);
        }
        if (SPLIT_OUT) {
            f16x8 hh, ll;
#pragma unroll
            for (int j = 0; j < 8; ++j) {
                f16 h = (f16)v[j];
                hh[j] = h;
                ll[j] = (f16)(v[j] - (float)h);
            }
            *(f16x8*)&outh[n * FOUT + c0] = hh;
            *(f16x8*)&outl[n * FOUT + c0] = ll;
        } else {
            *(float4*)&outf[n * FOUT + c0] = make_float4(v[0], v[1], v[2], v[3]);
            *(float4*)&outf[n * FOUT + c0 + 4] = make_float4(v[4], v[5], v[6], v[7]);
        }
    }
}

extern "C" void kernel_launch(void* const* d_in, const int* in_sizes, int n_in,
                              void* d_out, int out_size, void* d_ws, size_t ws_size,
                              hipStream_t stream) {
    const float* x = (const float*)d_in[0];
    const int* ei = (const int*)d_in[1];
    const float* W0 = (const float*)d_in[2];
    const float* as0 = (const float*)d_in[3];
    const float* ad0 = (const float*)d_in[4];
    const float* b0 = (const float*)d_in[5];
    const float* W1 = (const float*)d_in[6];
    const float* as1 = (const float*)d_in[7];
    const float* ad1 = (const float*)d_in[8];
    const float* b1 = (const float*)d_in[9];
    const float* W2 = (const float*)d_in[10];
    const float* as2 = (const float*)d_in[11];
    const float* ad2 = (const float*)d_in[12];
    const float* b2 = (const float*)d_in[13];

    const int N = in_sizes[0] / 128;   // 50000
    const int E = in_sizes[1] / 2;     // 800000
    const int NBK = (N + 255) >> 8;    // 196 coarse buckets (N < 65536)

    // workspace carve (all 16B-aligned)
    float* aS = (float*)d_ws;                  // N*4 f32
    float* aD = aS + (size_t)N * 4;            // N*4 f32
    f16* h16 = (f16*)(aD + (size_t)N * 4);     // N*128 f16
    f16* xh = h16 + (size_t)N * 128;           // N*128 f16
    f16* xl = xh + (size_t)N * 128;            // N*128 f16
    f16* w0h = xl + (size_t)N * 128;           // 128*128
    f16* w0l = w0h + 16384;
    f16* w1h = w0l + 16384;
    f16* w1l = w1h + 16384;
    f16* w2h = w1l + 16384;                    // 64*128
    f16* w2l = w2h + 8192;
    int* offsets = (int*)(w2l + 8192);         // N+1
    int* ssrc = offsets + N + 1;               // E (packed src|dst<<16)
    unsigned int* staging = (unsigned int*)(ssrc + E);  // E
    int* bcount = (int*)(staging + E);         // NBK
    int* bbase = bcount + NBK;                 // NBK+1
    int* bcursor = bbase + NBK + 1;            // NBK

    // ---- CSR build ----
    fill_zero_kernel<<<1, 256, 0, stream>>>(bcount, NBK);
    bucket_count_kernel<<<196, 256, 0, stream>>>(ei + E, E, bcount);
    bucket_scan_kernel<<<1, 256, 0, stream>>>(bcount, NBK, bbase, bcursor, offsets, N);
    bucket_scatter_kernel<<<(E + SC_TILE - 1) / SC_TILE, 256, 0, stream>>>(ei, ei + E, E, bcursor,
                                                                           staging);
    bucket_sort_kernel<<<NBK, 256, 0, stream>>>(staging, bbase, offsets, ssrc, N);

    // ---- splits ----
    split_x_kernel<<<(N * 32 + 255) / 256, 256, 0, stream>>>(x, xh, xl, N * 32);
    split_w_kernel<<<160, 256, 0, stream>>>(W0, W1, W2, w0h, w0l, w1h, w1l, w2h, w2l);

    const int gGemm = (N + 63) / 64;
    const int gAggr = (N + 3) / 4;

    // ---- layer 0 ----
    gemm_mfma_kernel<128, 4><<<gGemm, 256, 0, stream>>>(xh, xl, w0h, w0l, as0, ad0, h16, aS, aD, N);
    aggr_kernel<4, 32, true, true><<<gAggr, 256, 0, stream>>>(h16, aS, aD, b0, offsets, ssrc,
                                                              nullptr, xh, xl, N);
    // ---- layer 1 ----
    gemm_mfma_kernel<128, 4><<<gGemm, 256, 0, stream>>>(xh, xl, w1h, w1l, as1, ad1, h16, aS, aD, N);
    aggr_kernel<4, 32, true, true><<<gAggr, 256, 0, stream>>>(h16, aS, aD, b1, offsets, ssrc,
                                                              nullptr, xh, xl, N);
    // ---- layer 2 ----
    gemm_mfma_kernel<64, 1><<<gGemm, 256, 0, stream>>>(xh, xl, w2h, w2l, as2, ad2, h16, aS, aD, N);
    aggr_kernel<1, 64, false, false><<<gAggr, 256, 0, stream>>>(h16, aS, aD, b2, offsets, ssrc,
                                                                (float*)d_out, nullptr, nullptr,
                                                                N);
}

// Round 10
// 312.006 us; speedup vs baseline: 1.1175x; 1.0200x over previous
//
#include <hip/hip_runtime.h>

// GAT encoder, 3 layers. N=50000, E=800000, Fin=128.
// R9 -> R10: bucket_sort was 44.8us @ 84KB LDS, 196 blocks, 7% occupancy.
// Refined coarse buckets to dst>>6 (NBK=782, ~1023 edges each): sort LDS
// drops to ~34KB (4 blocks/CU), 782 blocks fill all CUs. Same deterministic
// 6x4-bit stable radix by (dlow<<16|src) - full-key canonical order, so
// ssrc stays bit-deterministic. Everything else unchanged from R9.

#define NEG_SLOPE 0.2f

typedef _Float16 f16;
typedef f16 f16x8 __attribute__((ext_vector_type(8)));
typedef f16 f16x4 __attribute__((ext_vector_type(4)));
typedef f16 f16x2 __attribute__((ext_vector_type(2)));
typedef float f32x4 __attribute__((ext_vector_type(4)));

#define BSH 6                    // coarse bucket = dst >> BSH
#define DLOWM 63                 // dlow mask (6 bits)
#define KEYBITS 22               // 6-bit dlow + 16-bit src

__device__ __forceinline__ float lrelu(float v) { return v > 0.f ? v : NEG_SLOPE * v; }

// ---------------- CSR build: two-level counting sort ----------------

__global__ void fill_zero_kernel(int* __restrict__ p, int n) {
    int i = blockIdx.x * blockDim.x + threadIdx.x;
    if (i < n) p[i] = 0;
}

__global__ __launch_bounds__(256) void bucket_count_kernel(const int* __restrict__ dst, int E,
                                                           int NBK, int* __restrict__ bcount) {
    __shared__ int lh[1024];
#pragma unroll
    for (int j = 0; j < 4; ++j) lh[threadIdx.x + j * 256] = 0;
    __syncthreads();
    int stride = gridDim.x * 256 * 4;
    for (int i = (blockIdx.x * 256 + threadIdx.x) * 4; i < E; i += stride) {
        int4 d = *(const int4*)&dst[i];
        atomicAdd(&lh[d.x >> BSH], 1);
        atomicAdd(&lh[d.y >> BSH], 1);
        atomicAdd(&lh[d.z >> BSH], 1);
        atomicAdd(&lh[d.w >> BSH], 1);
    }
    __syncthreads();
#pragma unroll
    for (int j = 0; j < 4; ++j) {
        int idx = threadIdx.x + j * 256;
        if (idx < NBK) {
            int v = lh[idx];
            if (v > 0) atomicAdd(&bcount[idx], v);
        }
    }
}

// Exclusive scan of NBK (<=1024) bucket counts; seeds bcursor; offsets[N]=E.
__global__ __launch_bounds__(256) void bucket_scan_kernel(const int* __restrict__ bcount, int NBK,
                                                          int* __restrict__ bbase,
                                                          int* __restrict__ bcursor,
                                                          int* __restrict__ offsets, int N) {
    int t = threadIdx.x;
    int chunk = (NBK + 255) / 256;
    int b0 = t * chunk, b1 = b0 + chunk;
    if (b0 > NBK) b0 = NBK;
    if (b1 > NBK) b1 = NBK;
    int s = 0;
    for (int i = b0; i < b1; ++i) s += bcount[i];
    int v = s;
    int lane = t & 63, wid = t >> 6;
#pragma unroll
    for (int off = 1; off < 64; off <<= 1) {
        int u = __shfl_up(v, off);
        if (lane >= off) v += u;
    }
    __shared__ int ws[4];
    if (lane == 63) ws[wid] = v;
    __syncthreads();
    int add = 0;
    for (int w = 0; w < wid; ++w) add += ws[w];
    v += add;
    int prefix = v - s;
    for (int i = b0; i < b1; ++i) {
        bbase[i] = prefix;
        bcursor[i] = prefix;
        prefix += bcount[i];
    }
    if (t == 255) {
        bbase[NBK] = v;
        offsets[N] = v;
    }
}

#define SC_TILE 4096
__global__ __launch_bounds__(256) void bucket_scatter_kernel(const int* __restrict__ src,
                                                             const int* __restrict__ dst, int E,
                                                             int* __restrict__ bcursor,
                                                             unsigned int* __restrict__ staging) {
    __shared__ int lh[1024];
    __shared__ int lcur[1024];
    int tid = threadIdx.x;
#pragma unroll
    for (int j = 0; j < 4; ++j) lh[tid + j * 256] = 0;
    __syncthreads();
    int base = blockIdx.x * SC_TILE + tid * 16;
    int sv[16], dv[16];
    bool act = base < E;
    if (act) {
#pragma unroll
        for (int q = 0; q < 4; ++q) {
            *(int4*)&sv[q * 4] = *(const int4*)&src[base + q * 4];
            *(int4*)&dv[q * 4] = *(const int4*)&dst[base + q * 4];
        }
#pragma unroll
        for (int j = 0; j < 16; ++j) atomicAdd(&lh[dv[j] >> BSH], 1);
    }
    __syncthreads();
#pragma unroll
    for (int j = 0; j < 4; ++j) {
        int idx = tid + j * 256;
        int c = lh[idx];
        if (c > 0) lcur[idx] = atomicAdd(&bcursor[idx], c);
    }
    __syncthreads();
    if (act) {
#pragma unroll
        for (int j = 0; j < 16; ++j) {
            int b = dv[j] >> BSH;
            int pos = atomicAdd(&lcur[b], 1);
            staging[pos] = (unsigned int)sv[j] | ((unsigned int)(dv[j] & DLOWM) << 16);
        }
    }
}

// One block per bucket. Deterministic stable LSD radix sort (6 x 4-bit) by
// key (dlow<<16 | src). Full-key order is canonical (ties = identical
// records), so ssrc is bit-deterministic regardless of scatter order.
#define SORT_CAP 2048
#define MIDX(f) ((f) + ((f) >> 4))
__global__ __launch_bounds__(256) void bucket_sort_kernel(const unsigned int* __restrict__ staging,
                                                          const int* __restrict__ bbase,
                                                          int* __restrict__ offsets,
                                                          int* __restrict__ ssrc, int N) {
    __shared__ unsigned int bufA[SORT_CAP];
    __shared__ unsigned int bufB[SORT_CAP];
    __shared__ int mat[4096 + 256];
    __shared__ int lh[64];
    __shared__ int wsum[4];
    int b = blockIdx.x;
    int tid = threadIdx.x;
    int s = bbase[b], e = bbase[b + 1];
    int cnt = e - s;
    bool fits = cnt <= SORT_CAP;

    if (tid < 64) lh[tid] = 0;
    __syncthreads();
    if (fits) {
        for (int i = tid; i < cnt; i += 256) {
            unsigned int r = staging[s + i];
            bufA[i] = r;
            atomicAdd(&lh[r >> 16], 1);
        }
    } else {
        for (int i = tid; i < cnt; i += 256) atomicAdd(&lh[staging[s + i] >> 16], 1);
    }
    __syncthreads();

    // offsets for this bucket's 64 dsts: single-wave scan (order-independent)
    int exc0 = 0;
    if (tid < 64) {
        int own = lh[tid];
        int v = own;
#pragma unroll
        for (int off = 1; off < 64; off <<= 1) {
            int u = __shfl_up(v, off);
            if (tid >= off) v += u;
        }
        exc0 = v - own;
        int dstn = (b << BSH) + tid;
        if (dstn < N) offsets[dstn] = s + exc0;
    }
    __syncthreads();

    int lane = tid & 63, wid = tid >> 6;
    if (fits) {
        unsigned int* in = bufA;
        unsigned int* out = bufB;
        int L = (cnt + 255) >> 8;
        int i0 = tid * L;
        int i1 = i0 + L;
        if (i0 > cnt) i0 = cnt;
        if (i1 > cnt) i1 = cnt;
        for (int sh = 0; sh < KEYBITS; sh += 4) {
            int c16[16];
#pragma unroll
            for (int d = 0; d < 16; ++d) c16[d] = 0;
            for (int i = i0; i < i1; ++i) c16[(in[i] >> sh) & 15]++;
#pragma unroll
            for (int d = 0; d < 16; ++d) mat[MIDX(d * 256 + tid)] = c16[d];
            __syncthreads();
            int base = tid * 16;
            int loc[16];
            int ssum = 0;
#pragma unroll
            for (int j = 0; j < 16; ++j) {
                loc[j] = ssum;
                ssum += mat[MIDX(base + j)];
            }
            int vv = ssum;
#pragma unroll
            for (int off = 1; off < 64; off <<= 1) {
                int u = __shfl_up(vv, off);
                if (lane >= off) vv += u;
            }
            if (lane == 63) wsum[wid] = vv;
            __syncthreads();
            int add2 = 0;
            for (int w = 0; w < wid; ++w) add2 += wsum[w];
            int exc2 = vv + add2 - ssum;
#pragma unroll
            for (int j = 0; j < 16; ++j) mat[MIDX(base + j)] = exc2 + loc[j];
            __syncthreads();
#pragma unroll
            for (int d = 0; d < 16; ++d) c16[d] = mat[MIDX(d * 256 + tid)];
            for (int i = i0; i < i1; ++i) {
                unsigned int r = in[i];
                int d = (r >> sh) & 15;
                out[c16[d]++] = r;
            }
            __syncthreads();
            unsigned int* tmp = in;
            in = out;
            out = tmp;
        }
        // 6 swaps (KEYBITS=22 -> ceil to 6 passes): wait, 22/4 = 5.5 -> loop
        // runs sh = 0,4,8,12,16,20 = 6 passes -> data back in bufA.
        for (int i = tid; i < cnt; i += 256) {
            unsigned int r = bufA[i];
            int dlow = (r >> 16) & DLOWM;
            unsigned int full = (r & 0xFFFFu) | ((unsigned int)((b << BSH) | dlow) << 16);
            ssrc[s + i] = (int)full;
        }
    } else {
        // fallback (cnt > SORT_CAP; ~32 sigma out for this E/NBK)
        if (tid < 64) lh[tid] = exc0;
        __syncthreads();
        for (int i = tid; i < cnt; i += 256) {
            unsigned int rec = staging[s + i];
            int dlow = rec >> 16;
            int r = atomicAdd(&lh[dlow], 1);
            unsigned int full = (rec & 0xFFFFu) | ((unsigned int)((b << BSH) | dlow) << 16);
            ssrc[s + r] = (int)full;
        }
    }
}

// ---------------- fp16 splits ----------------

__global__ void split_x_kernel(const float* __restrict__ x, f16* __restrict__ xh,
                               f16* __restrict__ xl, int total4) {
    int i = blockIdx.x * blockDim.x + threadIdx.x;
    if (i >= total4) return;
    float4 v = *(const float4*)&x[(size_t)i * 4];
    float vv[4] = {v.x, v.y, v.z, v.w};
    f16x4 h, l;
#pragma unroll
    for (int j = 0; j < 4; ++j) {
        f16 hj = (f16)vv[j];
        h[j] = hj;
        l[j] = (f16)(vv[j] - (float)hj);
    }
    *(f16x4*)&xh[(size_t)i * 4] = h;
    *(f16x4*)&xl[(size_t)i * 4] = l;
}

__global__ void split_w_kernel(const float* __restrict__ W0, const float* __restrict__ W1,
                               const float* __restrict__ W2, f16* __restrict__ w0h,
                               f16* __restrict__ w0l, f16* __restrict__ w1h,
                               f16* __restrict__ w1l, f16* __restrict__ w2h,
                               f16* __restrict__ w2l) {
    int idx = blockIdx.x * 256 + threadIdx.x;
    if (idx < 16384) {
        int k = idx >> 7, c = idx & 127;
        float v = W0[k * 128 + c];
        f16 h = (f16)v;
        w0h[c * 128 + k] = h;
        w0l[c * 128 + k] = (f16)(v - (float)h);
    } else if (idx < 32768) {
        int t = idx - 16384;
        int k = t >> 7, c = t & 127;
        float v = W1[k * 128 + c];
        f16 h = (f16)v;
        w1h[c * 128 + k] = h;
        w1l[c * 128 + k] = (f16)(v - (float)h);
    } else if (idx < 40960) {
        int t = idx - 32768;
        int k = t >> 6, c = t & 63;
        float v = W2[k * 64 + c];
        f16 h = (f16)v;
        w2h[c * 128 + k] = h;
        w2l[c * 128 + k] = (f16)(v - (float)h);
    }
}

// ---------------- split-fp16 MFMA GEMM + fused alpha dots ----------------
template <int FOUT, int H_>
__global__ __launch_bounds__(256) void gemm_mfma_kernel(
    const f16* __restrict__ Ah, const f16* __restrict__ Al, const f16* __restrict__ Bh,
    const f16* __restrict__ Bl, const float* __restrict__ a_src, const float* __restrict__ a_dst,
    f16* __restrict__ H16, float* __restrict__ asrc, float* __restrict__ adst, int N) {
    constexpr int CT = FOUT / 16;
    constexpr int TPH = CT / H_;
    __shared__ f16 lw[2][FOUT][72];
    int tid = threadIdx.x;
    int w = tid >> 6, lane = tid & 63;
    int quad = lane >> 4, m = lane & 15;
    int row0 = blockIdx.x * 64 + w * 16;
    int arow = row0 + m;
    if (arow >= N) arow = N - 1;
    const f16* aph = &Ah[(size_t)arow * 128 + quad * 8];
    const f16* apl = &Al[(size_t)arow * 128 + quad * 8];

    f32x4 acc[CT];
#pragma unroll
    for (int t = 0; t < CT; ++t) acc[t] = (f32x4){0.f, 0.f, 0.f, 0.f};

    for (int kh = 0; kh < 2; ++kh) {
        __syncthreads();
        for (int f = tid; f < FOUT * 8; f += 256) {
            int col = f >> 3, ch = f & 7;
            *(f16x8*)&lw[0][col][ch * 8] = *(const f16x8*)&Bh[(size_t)col * 128 + kh * 64 + ch * 8];
            *(f16x8*)&lw[1][col][ch * 8] = *(const f16x8*)&Bl[(size_t)col * 128 + kh * 64 + ch * 8];
        }
        __syncthreads();
#pragma unroll
        for (int kc = 0; kc < 2; ++kc) {
            f16x8 fah = *(const f16x8*)&aph[kh * 64 + kc * 32];
            f16x8 fal = *(const f16x8*)&apl[kh * 64 + kc * 32];
#pragma unroll
            for (int t = 0; t < CT; ++t) {
                f16x8 fbh = *(const f16x8*)&lw[0][t * 16 + m][kc * 32 + quad * 8];
                f16x8 fbl = *(const f16x8*)&lw[1][t * 16 + m][kc * 32 + quad * 8];
                acc[t] = __builtin_amdgcn_mfma_f32_16x16x32_f16(fah, fbh, acc[t], 0, 0, 0);
                acc[t] = __builtin_amdgcn_mfma_f32_16x16x32_f16(fal, fbh, acc[t], 0, 0, 0);
                acc[t] = __builtin_amdgcn_mfma_f32_16x16x32_f16(fah, fbl, acc[t], 0, 0, 0);
            }
        }
    }

    float asf[CT], adf[CT];
#pragma unroll
    for (int t = 0; t < CT; ++t) {
        asf[t] = a_src[t * 16 + m];
        adf[t] = a_dst[t * 16 + m];
    }

#pragma unroll
    for (int r = 0; r < 4; ++r) {
        int row = row0 + quad * 4 + r;
        f16 hq[CT];
        float hr[CT];
#pragma unroll
        for (int t = 0; t < CT; ++t) {
            hq[t] = (f16)acc[t][r];
            hr[t] = (float)hq[t];  // rounded: matches what aggr reads
        }
        float pa[H_], pd[H_];
#pragma unroll
        for (int hh = 0; hh < H_; ++hh) {
            pa[hh] = 0.f;
            pd[hh] = 0.f;
#pragma unroll
            for (int tt = 0; tt < TPH; ++tt) {
                int t = hh * TPH + tt;
                pa[hh] += hr[t] * asf[t];
                pd[hh] += hr[t] * adf[t];
            }
        }
#pragma unroll
        for (int mask = 1; mask < 16; mask <<= 1) {
#pragma unroll
            for (int hh = 0; hh < H_; ++hh) {
                pa[hh] += __shfl_xor(pa[hh], mask);
                pd[hh] += __shfl_xor(pd[hh], mask);
            }
        }
        if (row < N) {
#pragma unroll
            for (int t = 0; t < CT; ++t) H16[(size_t)row * FOUT + t * 16 + m] = hq[t];
#pragma unroll
            for (int hh = 0; hh < H_; ++hh) {
                if (m == hh) {
                    asrc[row * H_ + hh] = pa[hh];
                    adst[row * H_ + hh] = pd[hh];
                }
            }
        }
    }
}

// ---------------- aggregation: group-per-edge MLP, inline softmax weight ----------------
template <int H_, int C, bool RELU, bool SPLIT_OUT>
__global__ __launch_bounds__(256) void aggr_kernel(
    const f16* __restrict__ h16, const float* __restrict__ asrc,
    const float* __restrict__ adst, const float* __restrict__ bias,
    const int* __restrict__ offsets, const int* __restrict__ ssrc, float* __restrict__ outf,
    f16* __restrict__ outh, f16* __restrict__ outl, int N) {
    constexpr int FOUT = H_ * C;
    constexpr int LPG = FOUT / 8;
    constexpr int GROUPS = 64 / LPG;
    constexpr int UN = (GROUPS == 4) ? 4 : 2;
    int wid = threadIdx.x >> 6;
    int lane = threadIdx.x & 63;
    int n = blockIdx.x * 4 + wid;
    if (n >= N) return;
    int g = lane / LPG;
    int t = lane % LPG;
    int c0 = t * 8;
    int head = c0 / C;

    float adn = adst[n * H_ + head];
    float esf = lrelu(asrc[n * H_ + head] + adn);

    float D = 0.f;
    float S[8];
#pragma unroll
    for (int j = 0; j < 8; ++j) S[j] = 0.f;
    if (g == 0) {
        D = 1.f;
        f16x8 hv = *(const f16x8*)&h16[n * FOUT + c0];
#pragma unroll
        for (int j = 0; j < 8; ++j) S[j] = (float)hv[j];
    }

    int e1 = offsets[n + 1];
    int k = offsets[n] + g;

    for (; k + (UN - 1) * GROUPS < e1; k += UN * GROUPS) {
        int sarr[UN];
        float aval[UN];
        f16x8 hvv[UN];
#pragma unroll
        for (int u = 0; u < UN; ++u) sarr[u] = ssrc[k + u * GROUPS] & 0xFFFF;
#pragma unroll
        for (int u = 0; u < UN; ++u) {
            aval[u] = asrc[sarr[u] * H_ + head];
            hvv[u] = *(const f16x8*)&h16[sarr[u] * FOUT + c0];
        }
#pragma unroll
        for (int u = 0; u < UN; ++u) {
            float w = __expf(lrelu(aval[u] + adn) - esf);
            D += w;
#pragma unroll
            for (int j = 0; j < 8; ++j) S[j] += w * (float)hvv[u][j];
        }
    }
    for (; k < e1; k += GROUPS) {
        int s = ssrc[k] & 0xFFFF;
        float w = __expf(lrelu(asrc[s * H_ + head] + adn) - esf);
        f16x8 hv = *(const f16x8*)&h16[s * FOUT + c0];
        D += w;
#pragma unroll
        for (int j = 0; j < 8; ++j) S[j] += w * (float)hv[j];
    }

#pragma unroll
    for (int mask = LPG; mask < 64; mask <<= 1) {
        D += __shfl_xor(D, mask);
#pragma unroll
        for (int j = 0; j < 8; ++j) S[j] += __shfl_xor(S[j], mask);
    }

    if (g == 0) {
        float inv = 1.f / (D + 1e-16f);
        float v[8];
#pragma unroll
        for (int j = 0; j < 8; ++j) {
            v[j] = S[j] * inv + bias[c0 + j];
            if (RELU) v[j] = fmaxf(v[j], 0.f);
        }
        if (SPLIT_OUT) {
            f16x8 hh, ll;
#pragma unroll
            for (int j = 0; j < 8; ++j) {
                f16 h = (f16)v[j];
                hh[j] = h;
                ll[j] = (f16)(v[j] - (float)h);
            }
            *(f16x8*)&outh[n * FOUT + c0] = hh;
            *(f16x8*)&outl[n * FOUT + c0] = ll;
        } else {
            *(float4*)&outf[n * FOUT + c0] = make_float4(v[0], v[1], v[2], v[3]);
            *(float4*)&outf[n * FOUT + c0 + 4] = make_float4(v[4], v[5], v[6], v[7]);
        }
    }
}

extern "C" void kernel_launch(void* const* d_in, const int* in_sizes, int n_in,
                              void* d_out, int out_size, void* d_ws, size_t ws_size,
                              hipStream_t stream) {
    const float* x = (const float*)d_in[0];
    const int* ei = (const int*)d_in[1];
    const float* W0 = (const float*)d_in[2];
    const float* as0 = (const float*)d_in[3];
    const float* ad0 = (const float*)d_in[4];
    const float* b0 = (const float*)d_in[5];
    const float* W1 = (const float*)d_in[6];
    const float* as1 = (const float*)d_in[7];
    const float* ad1 = (const float*)d_in[8];
    const float* b1 = (const float*)d_in[9];
    const float* W2 = (const float*)d_in[10];
    const float* as2 = (const float*)d_in[11];
    const float* ad2 = (const float*)d_in[12];
    const float* b2 = (const float*)d_in[13];

    const int N = in_sizes[0] / 128;       // 50000
    const int E = in_sizes[1] / 2;         // 800000
    const int NBK = (N + (1 << BSH) - 1) >> BSH;  // 782 coarse buckets

    // workspace carve (all 16B-aligned)
    float* aS = (float*)d_ws;                  // N*4 f32
    float* aD = aS + (size_t)N * 4;            // N*4 f32
    f16* h16 = (f16*)(aD + (size_t)N * 4);     // N*128 f16
    f16* xh = h16 + (size_t)N * 128;           // N*128 f16
    f16* xl = xh + (size_t)N * 128;            // N*128 f16
    f16* w0h = xl + (size_t)N * 128;           // 128*128
    f16* w0l = w0h + 16384;
    f16* w1h = w0l + 16384;
    f16* w1l = w1h + 16384;
    f16* w2h = w1l + 16384;                    // 64*128
    f16* w2l = w2h + 8192;
    int* offsets = (int*)(w2l + 8192);         // N+1
    int* ssrc = offsets + N + 1;               // E (packed src|dst<<16)
    unsigned int* staging = (unsigned int*)(ssrc + E);  // E
    int* bcount = (int*)(staging + E);         // NBK
    int* bbase = bcount + NBK;                 // NBK+1
    int* bcursor = bbase + NBK + 1;            // NBK

    // ---- CSR build ----
    fill_zero_kernel<<<(NBK + 255) / 256, 256, 0, stream>>>(bcount, NBK);
    bucket_count_kernel<<<196, 256, 0, stream>>>(ei + E, E, NBK, bcount);
    bucket_scan_kernel<<<1, 256, 0, stream>>>(bcount, NBK, bbase, bcursor, offsets, N);
    bucket_scatter_kernel<<<(E + SC_TILE - 1) / SC_TILE, 256, 0, stream>>>(ei, ei + E, E, bcursor,
                                                                           staging);
    bucket_sort_kernel<<<NBK, 256, 0, stream>>>(staging, bbase, offsets, ssrc, N);

    // ---- splits ----
    split_x_kernel<<<(N * 32 + 255) / 256, 256, 0, stream>>>(x, xh, xl, N * 32);
    split_w_kernel<<<160, 256, 0, stream>>>(W0, W1, W2, w0h, w0l, w1h, w1l, w2h, w2l);

    const int gGemm = (N + 63) / 64;
    const int gAggr = (N + 3) / 4;

    // ---- layer 0 ----
    gemm_mfma_kernel<128, 4><<<gGemm, 256, 0, stream>>>(xh, xl, w0h, w0l, as0, ad0, h16, aS, aD, N);
    aggr_kernel<4, 32, true, true><<<gAggr, 256, 0, stream>>>(h16, aS, aD, b0, offsets, ssrc,
                                                              nullptr, xh, xl, N);
    // ---- layer 1 ----
    gemm_mfma_kernel<128, 4><<<gGemm, 256, 0, stream>>>(xh, xl, w1h, w1l, as1, ad1, h16, aS, aD, N);
    aggr_kernel<4, 32, true, true><<<gAggr, 256, 0, stream>>>(h16, aS, aD, b1, offsets, ssrc,
                                                              nullptr, xh, xl, N);
    // ---- layer 2 ----
    gemm_mfma_kernel<64, 1><<<gGemm, 256, 0, stream>>>(xh, xl, w2h, w2l, as2, ad2, h16, aS, aD, N);
    aggr_kernel<1, 64, false, false><<<gAggr, 256, 0, stream>>>(h16, aS, aD, b2, offsets, ssrc,
                                                                (float*)d_out, nullptr, nullptr,
                                                                N);
}